// Round 12
// baseline (373.946 us; speedup 1.0000x reference)
//
#include <hip/hip_runtime.h>

#pragma clang fp contract(off)

// TV-L1 optical flow inner scale (TVNet), B=8, H=W=480, 5 warps x 5 iters.
// Fused per warp step; region 50x40 = tile 40x30 + halo 5; 512 thr/block,
// 3 blocks/CU (LDS 48000 B). r12: VALU-issue bound -> vertical 4-row strips
// per thread: u,p state in REGISTERS (statically indexed), LDS only for
// neighbor exchange (spB written only on row 3; up/down neighbors come from
// registers for 3 of 4 rows). Per-pixel iteration masks collapse to a
// single compare vs precomputed t-bounds (box shrink is linear in t).
// grad / l_t*grad hoisted out of the iteration loop (iteration-invariant).
// ALL fp expressions, order, and selects identical to passing r4-r11
// (JAX-f32 linspace, contract off, left-to-right) -> bit-exact outputs.

constexpr int B = 8, H = 480, W = 480;
constexpr int HW = H * W;
constexpr int N = B * HW;

constexpr float THETA = (float)0.3;
constexpr float L_T  = (float)(0.15 * 0.3);   // python f64 product, cast f32
constexpr float TAUT = (float)(0.25 / 0.3);
constexpr float EPSF = (float)1e-12;

#define RW 50              // region width  (incl. halo)
#define RH 40              // region height
#define HALO 5
#define TW 40              // 480/12
#define TH 30              // 480/16
#define NTX 12
#define NTY 16
#define TPB 512
#define NSTRIP 500         // 50 cols x 10 row-strips
#define SJ 4               // rows per strip

// WARPK: 0=first (u from input arrays, p=0), 1=mid (ws float2/float4),
//        2=last (write u1/u2/rho outputs, skip final p-phase)
template <int WARPK>
__global__ __launch_bounds__(TPB, 4) void k_fused(
    const float* __restrict__ x1, const float* __restrict__ x2,
    const float* __restrict__ u1In, const float* __restrict__ u2In,
    const float2* __restrict__ uIn, const float4* __restrict__ pIn,
    float* __restrict__ u1Out, float* __restrict__ u2Out,
    float2* __restrict__ uOut, float4* __restrict__ pOut,
    float* __restrict__ rhoOut)
{
  __shared__ float2 su[RW * RH];    // {u1, u2}
  __shared__ float2 spA[RW * RH];   // {p11, p21}
  __shared__ float2 spB[RW * RH];   // {p12, p22}

  const int blk = blockIdx.x;
  const int bx = blk % NTX;
  const int by = (blk / NTX) % NTY;
  const int b  = blk / (NTX * NTY);
  const int ox = bx * TW - HALO;
  const int oy = by * TH - HALO;
  const int tid = threadIdx.x;
  const bool ok = (tid < NSTRIP);
  const int c  = tid % RW;          // column in region
  const int rs = tid / RW;          // row-strip index (0..9)
  const int pxc = ox + c;
  const int pyb = oy + rs * SJ;     // py of row j = pyb + j
  const int idxb = rs * SJ * RW + c;
  const bool bL = (pxc == 0), bR = (pxc == W - 1);
  const int base = b * HW;
  const float* __restrict__ im = x2 + base;

  // per-pixel register state (statically indexed via unrolled j loops)
  float ru1[SJ], ru2[SJ];                       // u
  float rp11[SJ], rp12[SJ], rp21[SJ], rp22[SJ]; // p
  float cdx[SJ], cdy[SJ], crc[SJ];              // warp constants
  float grd[SJ], ltg[SJ];                       // iteration-invariant
  int   tu[SJ], tp[SJ];                         // active iff t <= bound

  // ---- warp stage + t-bounds ----
#pragma unroll
  for (int j = 0; j < SJ; ++j) {
    const int py = pyb + j;
    const bool valid = ok && (pxc >= 0) && (pxc < W) && (py >= 0) && (py < H);
    if (valid) {
      int Lx = max(pxc - ox, -ox);
      int Ly = max(py - oy, -oy);
      int Rxu = (ox + RW >= W) ? 99 : (ox + RW - pxc);
      int Ryu = (oy + RH >= H) ? 99 : (oy + RH - py);
      tu[j] = min(min(Lx, Ly), min(Rxu, Ryu));
      int Rxp = (ox + RW >= W) ? 99 : (ox + RW - 1 - pxc);
      int Ryp = (oy + RH >= H) ? 99 : (oy + RH - 1 - py);
      tp[j] = min(min(Lx, Ly), min(Rxp, Ryp));
    } else { tu[j] = 0; tp[j] = 0; }
    if (valid) {
      const int gi = base + py * W + pxc;
      float u, v;
      if (WARPK == 0) { u = u1In[gi]; v = u2In[gi]; }
      else            { float2 uv = uIn[gi]; u = uv.x; v = uv.y; }
      // JAX f32 linspace: delta = 2/479 (f32 div), out = -1 + i*delta
      const float step = 2.0f / 479.0f;
      float gx = -1.0f + (float)pxc * step;
      float gy = -1.0f + (float)py * step;
      float X = ((gx + u * (float)(2.0 / 480.0)) + 1.0f) * 240.0f;
      float Y = ((gy + v * (float)(2.0 / 480.0)) + 1.0f) * 240.0f;
      float fX = floorf(X), fY = floorf(Y);
      int ix = (int)fX, iy = (int)fY;
      int x0i = min(max(ix, 0), W - 1);
      int x1i = min(max(ix + 1, 0), W - 1);
      int y0i = min(max(iy, 0), H - 1);
      int y1i = min(max(iy + 1, 0), H - 1);
      float x0f = (float)x0i, x1f = (float)x1i;
      float y0f = (float)y0i, y1f = (float)y1i;
      float wa = (x1f - X) * (y1f - Y);
      float wb = (x1f - X) * (Y - y0f);
      float wc = (X - x0f) * (y1f - Y);
      float wd = (X - x0f) * (Y - y0f);
      // hoisted clamped stencil indices (identical addresses/ops as r11)
      int xmA = max(x0i - 1, 0), xpA = min(x0i + 1, W - 1);
      int xmB = max(x1i - 1, 0), xpB = min(x1i + 1, W - 1);
      int ymA = max(y0i - 1, 0), ypA = min(y0i + 1, H - 1);
      int ymB = max(y1i - 1, 0), ypB = min(y1i + 1, H - 1);
      int y0W = y0i * W, y1W = y1i * W;
      int ymAW = ymA * W, ypAW = ypA * W, ymBW = ymB * W, ypBW = ypB * W;
      float Ia = im[y0W + x0i], Ib = im[y1W + x0i];
      float Ic = im[y0W + x1i], Id = im[y1W + x1i];
      float dA = 0.5f * (im[y0W + xpA] - im[y0W + xmA]);
      float dB = 0.5f * (im[y1W + xpA] - im[y1W + xmA]);
      float dC = 0.5f * (im[y0W + xpB] - im[y0W + xmB]);
      float dD = 0.5f * (im[y1W + xpB] - im[y1W + xmB]);
      float eA = 0.5f * (im[ypAW + x0i] - im[ymAW + x0i]);
      float eB = 0.5f * (im[ypBW + x0i] - im[ymBW + x0i]);
      float eC = 0.5f * (im[ypAW + x1i] - im[ymAW + x1i]);
      float eD = 0.5f * (im[ypBW + x1i] - im[ymBW + x1i]);
      float x2w = ((wa * Ia + wb * Ib) + wc * Ic) + wd * Id;
      float dxw = ((wa * dA + wb * dB) + wc * dC) + wd * dD;
      float dyw = ((wa * eA + wb * eB) + wc * eC) + wd * eD;
      cdx[j] = dxw; cdy[j] = dyw;
      crc[j] = ((x2w - dxw * u) - dyw * v) - x1[gi];
      // iteration-invariant (same value the loop used to recompute)
      grd[j] = (dxw * dxw + dyw * dyw) + EPSF;
      ltg[j] = L_T * grd[j];
      ru1[j] = u; ru2[j] = v;
      float4 q;
      if (WARPK == 0) q = make_float4(0.f, 0.f, 0.f, 0.f);
      else            q = pIn[gi];            // {p11,p12,p21,p22}
      rp11[j] = q.x; rp12[j] = q.y; rp21[j] = q.z; rp22[j] = q.w;
      const int idx = idxb + j * RW;
      spA[idx] = make_float2(q.x, q.z);       // {p11,p21}
      spB[idx] = make_float2(q.y, q.w);       // {p12,p22}
      // NOTE: no su init needed — first u-phase writes su before any read
    }
  }
  __syncthreads();

  // ---- 5 inner iterations ----
  for (int t = 1; t <= 5; ++t) {
    // u-phase
#pragma unroll
    for (int j = 0; j < SJ; ++j) {
      if (t <= tu[j]) {
        const int idx = idxb + j * RW;
        const int py = pyb + j;
        float dx = cdx[j], dy = cdy[j];
        float u = ru1[j], v = ru2[j];
        float rho = ((crc[j] + dx * u) + dy * v) + EPSF;
        float s;
        if (rho < -ltg[j])      s = L_T;
        else if (rho > ltg[j])  s = -L_T;
        else if (grd[j] > EPSF) s = (-rho) / grd[j];
        else                    s = 0.f;
        float v1 = s * dx + u;
        float v2 = s * dy + v;
        float2 pl = spA[idx - 1];             // left {p11,p21} (unused if bL)
        float pu12, pu22;                      // up {p12,p22}
        if (j == 0) { float2 q = spB[idx - RW]; pu12 = q.x; pu22 = q.y; }
        else        { pu12 = rp12[j - 1];       pu22 = rp22[j - 1]; }
        float dvx1, dvy1, dvx2, dvy2;
        if (bL)               dvx1 = rp11[j];
        else if (bR)          dvx1 = -pl.x;
        else                  dvx1 = rp11[j] - pl.x;
        if (py == 0)          dvy1 = rp12[j];
        else if (py == H - 1) dvy1 = -pu12;
        else                  dvy1 = rp12[j] - pu12;
        if (bL)               dvx2 = rp21[j];
        else if (bR)          dvx2 = -pl.y;
        else                  dvx2 = rp21[j] - pl.y;
        if (py == 0)          dvy2 = rp22[j];
        else if (py == H - 1) dvy2 = -pu22;
        else                  dvy2 = rp22[j] - pu22;
        float nu1 = v1 + THETA * (dvx1 + dvy1);
        float nu2 = v2 + THETA * (dvx2 + dvy2);
        ru1[j] = nu1; ru2[j] = nu2;
        if (!(WARPK == 2 && t == 5)) su[idx] = make_float2(nu1, nu2);
        if (WARPK == 2 && t == 5) {
          int ly = rs * SJ + j;
          if (c >= HALO && c < HALO + TW && ly >= HALO && ly < HALO + TH)
            rhoOut[base + py * W + pxc] = rho;
        }
      }
    }
    __syncthreads();

    // p-phase (skipped on last warp's final iteration)
    if (!(WARPK == 2 && t == 5)) {
#pragma unroll
      for (int j = 0; j < SJ; ++j) {
        if (t <= tp[j]) {
          const int idx = idxb + j * RW;
          const int py = pyb + j;
          float u1c = ru1[j], u2c = ru2[j];
          float2 uR = su[idx + 1];            // right (unused .x/.y if bR)
          float uD1, uD2;                      // down
          if (j < SJ - 1) { uD1 = ru1[j + 1]; uD2 = ru2[j + 1]; }
          else            { float2 q = su[idx + RW]; uD1 = q.x; uD2 = q.y; }
          float u1x = (pxc < W - 1) ? uR.x - u1c : 0.f;
          float u1y = (py  < H - 1) ? uD1  - u1c : 0.f;
          float u2x = (pxc < W - 1) ? uR.y - u2c : 0.f;
          float u2y = (py  < H - 1) ? uD2  - u2c : 0.f;
          float n1 = 1.0f + TAUT * sqrtf((u1x * u1x + u1y * u1y) + EPSF);
          float n2 = 1.0f + TAUT * sqrtf((u2x * u2x + u2y * u2y) + EPSF);
          float np11 = (rp11[j] + TAUT * u1x) / n1;
          float np12 = (rp12[j] + TAUT * u1y) / n1;
          float np21 = (rp21[j] + TAUT * u2x) / n2;
          float np22 = (rp22[j] + TAUT * u2y) / n2;
          rp11[j] = np11; rp12[j] = np12; rp21[j] = np21; rp22[j] = np22;
          spA[idx] = make_float2(np11, np21);
          if (j == SJ - 1) spB[idx] = make_float2(np12, np22);  // only row-3
        }
      }
      __syncthreads();
    }
  }

  // ---- write-out straight from registers (no barrier needed) ----
  if (ok && c >= HALO && c < HALO + TW) {
#pragma unroll
    for (int j = 0; j < SJ; ++j) {
      int ly = rs * SJ + j;
      if (ly >= HALO && ly < HALO + TH) {
        int gi = base + (pyb + j) * W + pxc;
        if (WARPK == 2) {
          u1Out[gi] = ru1[j];
          u2Out[gi] = ru2[j];
        } else {
          uOut[gi] = make_float2(ru1[j], ru2[j]);
          pOut[gi] = make_float4(rp11[j], rp12[j], rp21[j], rp22[j]);
        }
      }
    }
  }
}

extern "C" void kernel_launch(void* const* d_in, const int* in_sizes, int n_in,
                              void* d_out, int out_size, void* d_ws, size_t ws_size,
                              hipStream_t stream) {
  const float* x1 = (const float*)d_in[0];
  const float* x2 = (const float*)d_in[1];
  const float* u1_in = (const float*)d_in[2];
  const float* u2_in = (const float*)d_in[3];

  float* u1o  = (float*)d_out;
  float* u2o  = u1o + (size_t)N;
  float* rhoo = u1o + (size_t)2 * N;

  float* ws  = (float*)d_ws;
  float2* uA = (float2*)ws;                       // 2N floats
  float4* pA = (float4*)(ws + (size_t)2 * N);     // 4N floats (16B aligned)
  float2* uB = (float2*)(ws + (size_t)6 * N);     // 2N floats
  float4* pB = (float4*)(ws + (size_t)8 * N);     // 4N floats (16B aligned)

  dim3 grd(NTX * NTY * B), blk(TPB);
  k_fused<0><<<grd, blk, 0, stream>>>(x1, x2, u1_in, u2_in, nullptr, nullptr,
                                      nullptr, nullptr, uA, pA, rhoo);
  k_fused<1><<<grd, blk, 0, stream>>>(x1, x2, nullptr, nullptr, uA, pA,
                                      nullptr, nullptr, uB, pB, rhoo);
  k_fused<1><<<grd, blk, 0, stream>>>(x1, x2, nullptr, nullptr, uB, pB,
                                      nullptr, nullptr, uA, pA, rhoo);
  k_fused<1><<<grd, blk, 0, stream>>>(x1, x2, nullptr, nullptr, uA, pA,
                                      nullptr, nullptr, uB, pB, rhoo);
  k_fused<2><<<grd, blk, 0, stream>>>(x1, x2, nullptr, nullptr, uB, pB,
                                      u1o, u2o, nullptr, nullptr, rhoo);
}

// Round 13
// 354.610 us; speedup vs baseline: 1.0545x; 1.0545x over previous
//
#include <hip/hip_runtime.h>

#pragma clang fp contract(off)

// TV-L1 optical flow inner scale (TVNet), B=8, H=W=480, 5 warps x 5 iters.
// Fused per warp step; region 50x40 = tile 40x30 + halo 5; 512 thr/block,
// 3 blocks/CU (LDS 48000 B). r13 = r9's proven layout (LDS state, 0 bank
// conflicts, idx = tid + k*512) + only the verified-safe instruction cuts:
//  - t-bounds masking: per-phase activity = one compare vs precomputed
//    tu[k]/tp[k] (box shrink is linear in t; logic validated in r12)
//  - hoisted iteration-invariants: grad, l_t*grad, idx/px/py/gi/wout
//  - float2-u / float4-p workspace (one vector ld/st instead of 2/4)
//  - barrier trims on the final iteration (write-out reads own-thread
//    values only)
// ALL fp expressions, order, and selects identical to passing r4-r12
// (JAX-f32 linspace, contract off, left-to-right) -> bit-exact outputs.

constexpr int B = 8, H = 480, W = 480;
constexpr int HW = H * W;
constexpr int N = B * HW;

constexpr float THETA = (float)0.3;
constexpr float L_T  = (float)(0.15 * 0.3);   // python f64 product, cast f32
constexpr float TAUT = (float)(0.25 / 0.3);
constexpr float EPSF = (float)1e-12;

#define RW 50              // region width  (incl. halo)
#define RH 40              // region height
#define HALO 5
#define TW 40              // 480/12
#define TH 30              // 480/16
#define NTX 12
#define NTY 16
#define TPB 512
#define NPX 4              // ceil(50*40/512); k==3 partial (idx<2000)
#define RPX (RW*RH)        // 2000 region pixels

// WARPK: 0=first (u from input arrays, p=0), 1=mid (ws float2/float4),
//        2=last (write u1/u2/rho outputs, skip final p-phase)
template <int WARPK>
__global__ __launch_bounds__(TPB, 4) void k_fused(
    const float* __restrict__ x1, const float* __restrict__ x2,
    const float* __restrict__ u1In, const float* __restrict__ u2In,
    const float2* __restrict__ uIn, const float4* __restrict__ pIn,
    float* __restrict__ u1Out, float* __restrict__ u2Out,
    float2* __restrict__ uOut, float4* __restrict__ pOut,
    float* __restrict__ rhoOut)
{
  __shared__ float2 su[RPX];    // {u1, u2}
  __shared__ float2 spA[RPX];   // {p11, p21}
  __shared__ float2 spB[RPX];   // {p12, p22}

  const int blk = blockIdx.x;
  const int bx = blk % NTX;
  const int by = (blk / NTX) % NTY;
  const int b  = blk / (NTX * NTY);
  const int ox = bx * TW - HALO;
  const int oy = by * TH - HALO;
  const int tid = threadIdx.x;
  const int base = b * HW;
  const float* __restrict__ im = x2 + base;

  // per-pixel register constants (statically indexed via unrolled k loops)
  float cdx[NPX], cdy[NPX], crc[NPX];   // warp constants
  float grd[NPX], ltg[NPX];             // iteration-invariant
  int   idxA[NPX], pxA[NPX], pyA[NPX], giA[NPX];
  int   tu[NPX], tp[NPX];               // phase active iff t <= bound
  bool  wout[NPX];                      // tile-membership (write-out)

  // ---- warp stage + per-pixel precompute ----
#pragma unroll
  for (int k = 0; k < NPX; ++k) {
    const int idx = tid + k * TPB;
    idxA[k] = idx;
    const int ly = idx / RW, lx = idx - ly * RW;
    const int px = ox + lx, py = oy + ly;
    pxA[k] = px; pyA[k] = py;
    giA[k] = base + py * W + px;
    const bool inreg = (idx < RPX);
    const bool valid = inreg && (px >= 0) && (px < W) && (py >= 0) && (py < H);
    wout[k] = inreg && lx >= HALO && lx < HALO + TW &&
              ly >= HALO && ly < HALO + TH;
    if (valid) {
      // t-bounds (validated in r12): active iff t <= bound
      int Lx = max(px - ox, -ox);
      int Ly = max(py - oy, -oy);
      int Rxu = (ox + RW >= W) ? 99 : (ox + RW - px);
      int Ryu = (oy + RH >= H) ? 99 : (oy + RH - py);
      tu[k] = min(min(Lx, Ly), min(Rxu, Ryu));
      int Rxp = (ox + RW >= W) ? 99 : (ox + RW - 1 - px);
      int Ryp = (oy + RH >= H) ? 99 : (oy + RH - 1 - py);
      tp[k] = min(min(Lx, Ly), min(Rxp, Ryp));

      const int gi = giA[k];
      float u, v;
      if (WARPK == 0) { u = u1In[gi]; v = u2In[gi]; }
      else            { float2 uv = uIn[gi]; u = uv.x; v = uv.y; }
      // JAX f32 linspace: delta = 2/479 (f32 div), out = -1 + i*delta
      const float step = 2.0f / 479.0f;
      float gx = -1.0f + (float)px * step;
      float gy = -1.0f + (float)py * step;
      float X = ((gx + u * (float)(2.0 / 480.0)) + 1.0f) * 240.0f;
      float Y = ((gy + v * (float)(2.0 / 480.0)) + 1.0f) * 240.0f;
      float fX = floorf(X), fY = floorf(Y);
      int ix = (int)fX, iy = (int)fY;
      int x0i = min(max(ix, 0), W - 1);
      int x1i = min(max(ix + 1, 0), W - 1);
      int y0i = min(max(iy, 0), H - 1);
      int y1i = min(max(iy + 1, 0), H - 1);
      float x0f = (float)x0i, x1f = (float)x1i;
      float y0f = (float)y0i, y1f = (float)y1i;
      float wa = (x1f - X) * (y1f - Y);
      float wb = (x1f - X) * (Y - y0f);
      float wc = (X - x0f) * (y1f - Y);
      float wd = (X - x0f) * (Y - y0f);
      // hoisted clamped stencil indices (identical addresses/ops as r11)
      int xmA = max(x0i - 1, 0), xpA = min(x0i + 1, W - 1);
      int xmB = max(x1i - 1, 0), xpB = min(x1i + 1, W - 1);
      int ymA = max(y0i - 1, 0), ypA = min(y0i + 1, H - 1);
      int ymB = max(y1i - 1, 0), ypB = min(y1i + 1, H - 1);
      int y0W = y0i * W, y1W = y1i * W;
      int ymAW = ymA * W, ypAW = ypA * W, ymBW = ymB * W, ypBW = ypB * W;
      float Ia = im[y0W + x0i], Ib = im[y1W + x0i];
      float Ic = im[y0W + x1i], Id = im[y1W + x1i];
      float dA = 0.5f * (im[y0W + xpA] - im[y0W + xmA]);
      float dB = 0.5f * (im[y1W + xpA] - im[y1W + xmA]);
      float dC = 0.5f * (im[y0W + xpB] - im[y0W + xmB]);
      float dD = 0.5f * (im[y1W + xpB] - im[y1W + xmB]);
      float eA = 0.5f * (im[ypAW + x0i] - im[ymAW + x0i]);
      float eB = 0.5f * (im[ypBW + x0i] - im[ymBW + x0i]);
      float eC = 0.5f * (im[ypAW + x1i] - im[ymAW + x1i]);
      float eD = 0.5f * (im[ypBW + x1i] - im[ymBW + x1i]);
      float x2w = ((wa * Ia + wb * Ib) + wc * Ic) + wd * Id;
      float dxw = ((wa * dA + wb * dB) + wc * dC) + wd * dD;
      float dyw = ((wa * eA + wb * eB) + wc * eC) + wd * eD;
      cdx[k] = dxw; cdy[k] = dyw;
      crc[k] = ((x2w - dxw * u) - dyw * v) - x1[gi];
      // iteration-invariant (same values the loop used to recompute)
      grd[k] = (dxw * dxw + dyw * dyw) + EPSF;
      ltg[k] = L_T * grd[k];
      float4 q;
      if (WARPK == 0) q = make_float4(0.f, 0.f, 0.f, 0.f);
      else            q = pIn[gi];            // {p11,p12,p21,p22}
      su[idx]  = make_float2(u, v);
      spA[idx] = make_float2(q.x, q.z);       // {p11,p21}
      spB[idx] = make_float2(q.y, q.w);       // {p12,p22}
    } else { tu[k] = 0; tp[k] = 0; }
  }
  __syncthreads();

  // ---- 5 inner iterations ----
  for (int t = 1; t <= 5; ++t) {
    // u-phase: reads own u/p + left/up p pairs (LDS), writes u (LDS)
#pragma unroll
    for (int k = 0; k < NPX; ++k) {
      if (t <= tu[k]) {
        const int idx = idxA[k];
        float2 uo  = su[idx];
        float2 pAo = spA[idx];        // {p11, p21} own
        float2 pBo = spB[idx];        // {p12, p22} own
        float2 pl = spA[idx - 1];     // {p11, p21} left  (unused if px==0)
        float2 pu = spB[idx - RW];    // {p12, p22} up    (unused if py==0)
        float dx = cdx[k], dy = cdy[k];
        float u = uo.x, v = uo.y;
        float rho = ((crc[k] + dx * u) + dy * v) + EPSF;
        float s;
        if (rho < -ltg[k])      s = L_T;
        else if (rho > ltg[k])  s = -L_T;
        else if (grd[k] > EPSF) s = (-rho) / grd[k];
        else                    s = 0.f;
        float v1 = s * dx + u;
        float v2 = s * dy + v;
        const int px = pxA[k], py = pyA[k];
        float dvx1, dvy1, dvx2, dvy2;
        if (px == 0)          dvx1 = pAo.x;
        else if (px == W - 1) dvx1 = -pl.x;
        else                  dvx1 = pAo.x - pl.x;
        if (py == 0)          dvy1 = pBo.x;
        else if (py == H - 1) dvy1 = -pu.x;
        else                  dvy1 = pBo.x - pu.x;
        if (px == 0)          dvx2 = pAo.y;
        else if (px == W - 1) dvx2 = -pl.y;
        else                  dvx2 = pAo.y - pl.y;
        if (py == 0)          dvy2 = pBo.y;
        else if (py == H - 1) dvy2 = -pu.y;
        else                  dvy2 = pBo.y - pu.y;
        float nu1 = v1 + THETA * (dvx1 + dvy1);
        float nu2 = v2 + THETA * (dvx2 + dvy2);
        su[idx] = make_float2(nu1, nu2);
        if (WARPK == 2 && t == 5 && wout[k])
          rhoOut[giA[k]] = rho;
      }
    }
    if (WARPK == 2 && t == 5) break;   // write-out reads own su only
    __syncthreads();

    // p-phase: reads own/right/down u + own p (LDS), writes p (LDS)
#pragma unroll
    for (int k = 0; k < NPX; ++k) {
      if (t <= tp[k]) {
        const int idx = idxA[k];
        float2 uo = su[idx];
        float2 uR = su[idx + 1];     // unused when px==W-1 (pad-safe)
        float2 uD = su[idx + RW];    // unused when py==H-1
        float2 pAo = spA[idx];
        float2 pBo = spB[idx];
        const int px = pxA[k], py = pyA[k];
        float u1c = uo.x, u2c = uo.y;
        float u1x = (px < W - 1) ? uR.x - u1c : 0.f;
        float u1y = (py < H - 1) ? uD.x - u1c : 0.f;
        float u2x = (px < W - 1) ? uR.y - u2c : 0.f;
        float u2y = (py < H - 1) ? uD.y - u2c : 0.f;
        float n1 = 1.0f + TAUT * sqrtf((u1x * u1x + u1y * u1y) + EPSF);
        float n2 = 1.0f + TAUT * sqrtf((u2x * u2x + u2y * u2y) + EPSF);
        float np11 = (pAo.x + TAUT * u1x) / n1;
        float np12 = (pBo.x + TAUT * u1y) / n1;
        float np21 = (pAo.y + TAUT * u2x) / n2;
        float np22 = (pBo.y + TAUT * u2y) / n2;
        spA[idx] = make_float2(np11, np21);
        spB[idx] = make_float2(np12, np22);
      }
    }
    if (t < 5) __syncthreads();   // final p-phase: write-out reads own only
  }

  // ---- write-out: tile pixels straight from own LDS entries ----
#pragma unroll
  for (int k = 0; k < NPX; ++k) {
    if (wout[k]) {
      const int gi = giA[k];
      float2 uo = su[idxA[k]];
      if (WARPK == 2) {
        u1Out[gi] = uo.x;
        u2Out[gi] = uo.y;
      } else {
        uOut[gi] = uo;
        float2 a = spA[idxA[k]], c = spB[idxA[k]];
        pOut[gi] = make_float4(a.x, c.x, a.y, c.y);  // {p11,p12,p21,p22}
      }
    }
  }
}

extern "C" void kernel_launch(void* const* d_in, const int* in_sizes, int n_in,
                              void* d_out, int out_size, void* d_ws, size_t ws_size,
                              hipStream_t stream) {
  const float* x1 = (const float*)d_in[0];
  const float* x2 = (const float*)d_in[1];
  const float* u1_in = (const float*)d_in[2];
  const float* u2_in = (const float*)d_in[3];

  float* u1o  = (float*)d_out;
  float* u2o  = u1o + (size_t)N;
  float* rhoo = u1o + (size_t)2 * N;

  float* ws  = (float*)d_ws;
  float2* uA = (float2*)ws;                       // 2N floats
  float4* pA = (float4*)(ws + (size_t)2 * N);     // 4N floats (16B aligned)
  float2* uB = (float2*)(ws + (size_t)6 * N);     // 2N floats
  float4* pB = (float4*)(ws + (size_t)8 * N);     // 4N floats (16B aligned)

  dim3 grd(NTX * NTY * B), blk(TPB);
  k_fused<0><<<grd, blk, 0, stream>>>(x1, x2, u1_in, u2_in, nullptr, nullptr,
                                      nullptr, nullptr, uA, pA, rhoo);
  k_fused<1><<<grd, blk, 0, stream>>>(x1, x2, nullptr, nullptr, uA, pA,
                                      nullptr, nullptr, uB, pB, rhoo);
  k_fused<1><<<grd, blk, 0, stream>>>(x1, x2, nullptr, nullptr, uB, pB,
                                      nullptr, nullptr, uA, pA, rhoo);
  k_fused<1><<<grd, blk, 0, stream>>>(x1, x2, nullptr, nullptr, uA, pA,
                                      nullptr, nullptr, uB, pB, rhoo);
  k_fused<2><<<grd, blk, 0, stream>>>(x1, x2, nullptr, nullptr, uB, pB,
                                      u1o, u2o, nullptr, nullptr, rhoo);
}